// Round 8
// baseline (146.218 us; speedup 1.0000x reference)
//
#include <hip/hip_runtime.h>
#include <hip/hip_fp16.h>
#include <math.h>
#include <string.h>

#define Dd 192
#define Hh 192
#define Ww 192
#define K  11
#define R  5

#define TW 32             // tile width (output cols)
#define TH 16             // tile height (output rows)
#define DC 12             // output planes per chunk (22 input planes)
#define NP 22             // input planes per chunk
#define NT 256            // threads per block (4 waves)
#define NQ 8              // output quads (4-col groups) per row
#define HH_ 26            // halo rows = TH + 2R
#define SQUADS 12         // staged aligned quads per row (48 cols)
#define SP 26             // stg row stride in dwords (24 data + 2 pad)
#define CS 16             // cwl row stride in dwords
#define NSTG (HH_ * SQUADS)   // 312 staging tasks
#define NCW  (HH_ * NQ)       // 208 conv-W tasks

struct GW { unsigned int g2[K]; };   // half2(g,g) bit patterns

static __device__ __forceinline__ __half2 u2h2(unsigned int u) {
    union { unsigned int u; __half2 h; } x; x.u = u; return x.h;
}
static __device__ __forceinline__ unsigned int h22u(__half2 h) {
    union { __half2 h; unsigned int u; } x; x.h = h; return x.u;
}
static __device__ __forceinline__ unsigned int pk(float a, float b) {
    typedef __fp16 f16x2 __attribute__((ext_vector_type(2)));
    f16x2 r = __builtin_amdgcn_cvt_pkrtz(a, b);
    union { f16x2 v; unsigned int u; } x; x.v = r; return x.u;
}

// Software-pipelined fused SSIM:
//   iter ip:  conv-H(ip) | conv-W(ip+1) | stage-write(ip+2) | load(ip+3) | bar
// Double-buffered stg/cwl make all intra-iteration phases independent;
// waves 0-1 run conv-H/ring/SSIM, waves 2-3 run staging+conv-W.
__global__ __launch_bounds__(NT, 2) void fused_ssim(
    const float* __restrict__ gr, const float* __restrict__ gt,
    GW gw, double* __restrict__ acc_g)
{
    __shared__ __align__(16) unsigned int stg[2][2][HH_][SP];  // [buf][x/y]
    __shared__ __align__(16) unsigned int cwl[2][5][HH_][CS];  // [buf][field]
    __shared__ float wsum[NT / 64];

    const int tid = threadIdx.x;
    const int q   = tid & (NQ - 1);
    const int th  = (tid >> 3) & 15;
    const int w0  = blockIdx.x * TW;
    const int h0  = blockIdx.y * TH;
    const int d0  = blockIdx.z * DC;

    // staging tasks: threads 128..255 take {tid-128, tid}; threads 0..55 take {256+tid}
    int  saddr[2]; bool sok[2]; int srow[2], scc[2]; bool sact[2];
#pragma unroll
    for (int k = 0; k < 2; ++k) {
        int t; bool a;
        if (k == 0) { a = (tid >= 128) || (tid < 56); t = (tid >= 128) ? (tid - 128) : (256 + tid); }
        else        { a = (tid >= 128); t = tid; }
        sact[k] = a;
        const int tt = a ? t : 0;
        const int r  = tt / SQUADS;
        const int cc = tt - r * SQUADS;
        srow[k] = r; scc[k] = cc;
        const int gh   = h0 - R + r;
        const bool rok = a && (gh >= 0) && (gh < Hh);
        const int ghc  = gh < 0 ? 0 : (gh >= Hh ? Hh - 1 : gh);
        const int gx0  = w0 - 8 + 4 * cc;              // aligned quad start
        const bool qok = (gx0 >= 0) && (gx0 + 3 < Ww);
        const int gxc  = gx0 < 0 ? 0 : (gx0 > Ww - 4 ? Ww - 4 : gx0);
        saddr[k] = ghc * Ww + gxc;
        sok[k]   = rok && qok;
    }

    const int cwu = tid - 128;   // conv-W: tasks cwu and cwu+128 (if valid)

    float4 px[2], py[2];

    auto LOAD = [&](int p) {
        const int z = d0 - R + p;
        const bool zok = (z >= 0) && (z < Dd);
        const int zb = (zok ? z : 0) * Hh * Ww;
#pragma unroll
        for (int k = 0; k < 2; ++k) if (sact[k]) {
            const float4 vx = *(const float4*)(gr + zb + saddr[k]);
            const float4 vy = *(const float4*)(gt + zb + saddr[k]);
            const bool ok = sok[k] && zok;
            px[k].x = ok ? vx.x : -1.f; px[k].y = ok ? vx.y : -1.f;
            px[k].z = ok ? vx.z : -1.f; px[k].w = ok ? vx.w : -1.f;
            py[k].x = ok ? vy.x : -1.f; py[k].y = ok ? vy.y : -1.f;
            py[k].z = ok ? vy.z : -1.f; py[k].w = ok ? vy.w : -1.f;
        }
    };

    auto STORE = [&](int p) {
        const int b = p & 1;
#pragma unroll
        for (int k = 0; k < 2; ++k) if (sact[k]) {
            uint2 vx, vy;
            vx.x = pk(fmaf(px[k].x, .5f, .5f), fmaf(px[k].y, .5f, .5f));
            vx.y = pk(fmaf(px[k].z, .5f, .5f), fmaf(px[k].w, .5f, .5f));
            vy.x = pk(fmaf(py[k].x, .5f, .5f), fmaf(py[k].y, .5f, .5f));
            vy.y = pk(fmaf(py[k].z, .5f, .5f), fmaf(py[k].w, .5f, .5f));
            *(uint2*)&stg[b][0][srow[k]][2 * scc[k]] = vx;
            *(uint2*)&stg[b][1][srow[k]][2 * scc[k]] = vy;
        }
    };

    auto CONVW1 = [&](int p, int task) {
        const int b  = p & 1;
        const int r  = task >> 3;
        const int qq = task & (NQ - 1);
        unsigned int dx[10], dy[10];
#pragma unroll
        for (int u = 0; u < 5; ++u) {
            const uint2 vx = *(const uint2*)&stg[b][0][r][2 * qq + 2 * u];
            const uint2 vy = *(const uint2*)&stg[b][1][r][2 * qq + 2 * u];
            dx[2 * u] = vx.x; dx[2 * u + 1] = vx.y;
            dy[2 * u] = vy.x; dy[2 * u + 1] = vy.y;
        }
        __half2 aA[5], aB[5];
#pragma unroll
        for (int f = 0; f < 5; ++f) { aA[f] = u2h2(0u); aB[f] = u2h2(0u); }
#pragma unroll
        for (int t5 = 0; t5 < K; ++t5) {
            const int bb = t5 + 3;       // starting half index (window @ -8)
            unsigned int xa, xb, ya, yb;
            if ((bb & 1) == 0) {
                xa = dx[bb >> 1]; xb = dx[(bb >> 1) + 1];
                ya = dy[bb >> 1]; yb = dy[(bb >> 1) + 1];
            } else {
                xa = __builtin_amdgcn_alignbit(dx[(bb + 1) >> 1], dx[bb >> 1], 16);
                xb = __builtin_amdgcn_alignbit(dx[(bb + 3) >> 1], dx[(bb + 1) >> 1], 16);
                ya = __builtin_amdgcn_alignbit(dy[(bb + 1) >> 1], dy[bb >> 1], 16);
                yb = __builtin_amdgcn_alignbit(dy[(bb + 3) >> 1], dy[(bb + 1) >> 1], 16);
            }
            const __half2 g   = u2h2(gw.g2[t5]);
            const __half2 hxa = u2h2(xa), hxb = u2h2(xb);
            const __half2 hya = u2h2(ya), hyb = u2h2(yb);
            aA[0] = __hfma2(g, hxa, aA[0]);  aB[0] = __hfma2(g, hxb, aB[0]);
            aA[1] = __hfma2(g, hya, aA[1]);  aB[1] = __hfma2(g, hyb, aB[1]);
            aA[2] = __hfma2(g, __hmul2(hxa, hxa), aA[2]);
            aB[2] = __hfma2(g, __hmul2(hxb, hxb), aB[2]);
            aA[3] = __hfma2(g, __hmul2(hya, hya), aA[3]);
            aB[3] = __hfma2(g, __hmul2(hyb, hyb), aB[3]);
            aA[4] = __hfma2(g, __hmul2(hxa, hya), aA[4]);
            aB[4] = __hfma2(g, __hmul2(hxb, hyb), aB[4]);
        }
#pragma unroll
        for (int f = 0; f < 5; ++f) {
            uint2 o; o.x = h22u(aA[f]); o.y = h22u(aB[f]);
            *(uint2*)&cwl[b][f][r][2 * qq] = o;
        }
    };

    auto CONVW = [&](int p) {
        if (cwu >= 0)                    CONVW1(p, cwu);
        if (cwu >= 0 && cwu < NCW - 128) CONVW1(p, cwu + 128);
    };

    unsigned int hist[K][5][2];   // conv-D ring (fp16 pairs, 4 cols)
#pragma unroll
    for (int t = 0; t < K; ++t)
#pragma unroll
        for (int f = 0; f < 5; ++f) { hist[t][f][0] = 0u; hist[t][f][1] = 0u; }

    float ssim_acc = 0.0f;

    // ---- pipeline prologue ----
    LOAD(0);
    STORE(0); LOAD(1); __syncthreads();
    CONVW(0); STORE(1); LOAD(2); __syncthreads();

    // ---- main loop: one barrier per plane ----
    for (int c = 0; c < 2; ++c) {
#pragma unroll
        for (int j = 0; j < K; ++j) {
            const int ip = c * K + j;
            const int rb = (c + j) & 1;        // == ip & 1

            // conv-H(ip) + ring insert + conv-D/SSIM  (waves 0-1)
            if (tid < TH * NQ) {
                __half2 cA[5], cB[5];
#pragma unroll
                for (int f = 0; f < 5; ++f) { cA[f] = u2h2(0u); cB[f] = u2h2(0u); }
#pragma unroll
                for (int t6 = 0; t6 < K; ++t6) {
                    const __half2 g = u2h2(gw.g2[t6]);
#pragma unroll
                    for (int f = 0; f < 5; ++f) {
                        const uint2 v = *(const uint2*)&cwl[rb][f][th + t6][2 * q];
                        cA[f] = __hfma2(g, u2h2(v.x), cA[f]);
                        cB[f] = __hfma2(g, u2h2(v.y), cB[f]);
                    }
                }
#pragma unroll
                for (int f = 0; f < 5; ++f) {
                    hist[j][f][0] = h22u(cA[f]);
                    hist[j][f][1] = h22u(cB[f]);
                }

                if (ip >= 2 * R) {
                    __half2 sA[5], sB[5];
#pragma unroll
                    for (int f = 0; f < 5; ++f) { sA[f] = u2h2(0u); sB[f] = u2h2(0u); }
#pragma unroll
                    for (int t7 = 0; t7 < K; ++t7) {
                        const int s = (j + 1 + t7) % K;   // static after unroll
                        const __half2 g = u2h2(gw.g2[t7]);
#pragma unroll
                        for (int f = 0; f < 5; ++f) {
                            sA[f] = __hfma2(g, u2h2(hist[s][f][0]), sA[f]);
                            sB[f] = __hfma2(g, u2h2(hist[s][f][1]), sB[f]);
                        }
                    }
                    const float C1 = 1e-4f, C2 = 9e-4f;
#pragma unroll
                    for (int hv = 0; hv < 2; ++hv) {
                        const __half2 v0 = hv ? sB[0] : sA[0];
                        const __half2 v1 = hv ? sB[1] : sA[1];
                        const __half2 v2 = hv ? sB[2] : sA[2];
                        const __half2 v3 = hv ? sB[3] : sA[3];
                        const __half2 v4 = hv ? sB[4] : sA[4];
#pragma unroll
                        for (int col = 0; col < 2; ++col) {
                            const float m1  = col ? __high2float(v0) : __low2float(v0);
                            const float m2  = col ? __high2float(v1) : __low2float(v1);
                            const float e11 = col ? __high2float(v2) : __low2float(v2);
                            const float e22 = col ? __high2float(v3) : __low2float(v3);
                            const float e12 = col ? __high2float(v4) : __low2float(v4);
                            const float mu1sq = m1 * m1, mu2sq = m2 * m2, mu12 = m1 * m2;
                            const float s11 = e11 - mu1sq;
                            const float s22 = e22 - mu2sq;
                            const float s12 = e12 - mu12;
                            const float num = (2.f * mu12 + C1) * (2.f * s12 + C2);
                            const float den = (mu1sq + mu2sq + C1) * (s11 + s22 + C2);
                            ssim_acc += num * __builtin_amdgcn_rcpf(den);
                        }
                    }
                }
            }

            if (ip + 1 < NP) CONVW(ip + 1);    // waves 2-3
            if (ip + 2 < NP) STORE(ip + 2);
            if (ip + 3 < NP) LOAD(ip + 3);
            if (ip < NP - 1) __syncthreads();
        }
    }

    // ---- block reduction + one atomic ----
    float v = ssim_acc;
#pragma unroll
    for (int o = 32; o > 0; o >>= 1) v += __shfl_down(v, o);
    const int lane = tid & 63;
    const int wid  = tid >> 6;
    if (lane == 0) wsum[wid] = v;
    __syncthreads();
    if (tid == 0) {
        float s = 0.f;
#pragma unroll
        for (int i = 0; i < NT / 64; ++i) s += wsum[i];
        atomicAdd(acc_g, (double)s);
    }
}

__global__ void k4_final(const double* __restrict__ acc, float* __restrict__ out) {
    if (threadIdx.x == 0) {
        const double n = (double)((size_t)Dd * Hh * Ww);
        out[0] = (float)(1.0 - (*acc) / n);
    }
}

// host-side float -> half (RNE)
static unsigned short f2h(float x) {
    unsigned int u; memcpy(&u, &x, 4);
    unsigned int s = (u >> 16) & 0x8000u;
    int e = (int)((u >> 23) & 0xffu) - 112;
    unsigned int m = u & 0x7fffffu;
    if (e <= 0) return (unsigned short)s;
    unsigned int mant = m + 0xFFFu + ((m >> 13) & 1u);
    if (mant & 0x800000u) { mant = 0; e += 1; }
    return (unsigned short)(s | ((unsigned)e << 10) | (mant >> 13));
}

extern "C" void kernel_launch(void* const* d_in, const int* in_sizes, int n_in,
                              void* d_out, int out_size, void* d_ws, size_t ws_size,
                              hipStream_t stream) {
    const float* gr = (const float*)d_in[0];
    const float* gt = (const float*)d_in[1];
    float* out = (float*)d_out;

    // 1D normalized gaussian (exact outer-product factorization of the 3D window)
    GW gw;
    {
        double e[K], s = 0.0;
        for (int i = 0; i < K; ++i) {
            const double a = (double)((i - R) * (i - R));
            e[i] = exp(-a / (2.0 * 1.5 * 1.5));
            s += e[i];
        }
        for (int i = 0; i < K; ++i) {
            unsigned short h = f2h((float)(e[i] / s));
            gw.g2[i] = (unsigned int)h | ((unsigned int)h << 16);
        }
    }

    double* acc = (double*)d_ws;
    (void)hipMemsetAsync(d_ws, 0, sizeof(double), stream);

    dim3 grid(Ww / TW, Hh / TH, Dd / DC);   // 6 x 12 x 16 = 1152 blocks
    fused_ssim<<<grid, NT, 0, stream>>>(gr, gt, gw, acc);

    k4_final<<<1, 64, 0, stream>>>(acc, out);
}

// Round 9
// 114.791 us; speedup vs baseline: 1.2738x; 1.2738x over previous
//
#include <hip/hip_runtime.h>
#include <hip/hip_fp16.h>
#include <math.h>
#include <string.h>

#define Dd 192
#define Hh 192
#define Ww 192
#define K  11
#define R  5

#define TW 16             // wave tile width (output cols)
#define TH 6              // wave tile height (output rows)
#define DC 12             // output planes per chunk
#define NP 22             // input planes per chunk
#define HR 16             // halo rows = TH + 2R
#define SP 20             // stg row stride in dwords (16 data + 4 pad)
#define CS 12             // cwl row stride in dwords (8 data + 4 pad)
// staging: 16 rows x 8 quads = 128 tasks = 2/lane (exact)
// conv-W : 16 rows x 4 quads =  64 tasks = 1/lane (exact)
// conv-H : 6 rows x 8 col-pairs = 48 tasks (lanes 48-63 idle there)

struct GW { unsigned int g2[K]; };   // half2(g,g) bit patterns

static __device__ __forceinline__ __half2 u2h2(unsigned int u) {
    union { unsigned int u; __half2 h; } x; x.u = u; return x.h;
}
static __device__ __forceinline__ unsigned int h22u(__half2 h) {
    union { __half2 h; unsigned int u; } x; x.h = h; return x.u;
}
static __device__ __forceinline__ unsigned int pk(float a, float b) {
    typedef __fp16 f16x2 __attribute__((ext_vector_type(2)));
    f16x2 r = __builtin_amdgcn_cvt_pkrtz(a, b);
    union { f16x2 v; unsigned int u; } x; x.v = r; return x.u;
}

// Wave-level phase fence: drain all our DS ops, pin compiler/scheduler order.
// Makes each wave's stage->convW->convH chain correct with NO __syncthreads.
#define FENCE() do { asm volatile("s_waitcnt lgkmcnt(0)" ::: "memory"); \
                     __builtin_amdgcn_sched_barrier(0); } while (0)

__global__ __launch_bounds__(256, 4) void fused_ssim(
    const float* __restrict__ gr, const float* __restrict__ gt,
    GW gw, double* __restrict__ acc_g)
{
    __shared__ __align__(16) unsigned int stg[4][2][HR][SP];  // per-wave x,y
    __shared__ __align__(16) unsigned int cwl[4][5][HR][CS];  // per-wave conv-W out
    __shared__ float wsum[4];

    const int tid  = threadIdx.x;
    const int wv   = tid >> 6;
    const int lane = tid & 63;

    const int w0 = (blockIdx.x * 4 + wv) * TW;
    const int h0 = blockIdx.y * TH;
    const int d0 = blockIdx.z * DC;

    // ---- staging geometry: exactly 2 float4-pair tasks per lane ----
    int saddr[2]; bool sok[2]; int srow[2], scc[2];
#pragma unroll
    for (int k = 0; k < 2; ++k) {
        const int t  = lane + 64 * k;
        const int r  = t >> 3;
        const int cc = t & 7;
        srow[k] = r; scc[k] = cc;
        const int gh   = h0 - R + r;
        const bool rok = (gh >= 0) && (gh < Hh);
        const int ghc  = gh < 0 ? 0 : (gh >= Hh ? Hh - 1 : gh);
        const int gx0  = w0 - 8 + 4 * cc;              // aligned quad start
        const bool qok = (gx0 >= 0) && (gx0 + 3 < Ww);
        const int gxc  = gx0 < 0 ? 0 : (gx0 > Ww - 4 ? Ww - 4 : gx0);
        saddr[k] = ghc * Ww + gxc;
        sok[k]   = rok && qok;
    }

    float4 px[2], py[2];

    auto LOAD = [&](int p) {
        const int z = d0 - R + p;
        const bool zok = (z >= 0) && (z < Dd);
        const int zb = (zok ? z : 0) * Hh * Ww;
#pragma unroll
        for (int k = 0; k < 2; ++k) {
            const float4 vx = *(const float4*)(gr + zb + saddr[k]);
            const float4 vy = *(const float4*)(gt + zb + saddr[k]);
            const bool ok = sok[k] && zok;
            px[k].x = ok ? vx.x : -1.f; px[k].y = ok ? vx.y : -1.f;
            px[k].z = ok ? vx.z : -1.f; px[k].w = ok ? vx.w : -1.f;
            py[k].x = ok ? vy.x : -1.f; py[k].y = ok ? vy.y : -1.f;
            py[k].z = ok ? vy.z : -1.f; py[k].w = ok ? vy.w : -1.f;
        }
    };

    auto STORE = [&]() {
#pragma unroll
        for (int k = 0; k < 2; ++k) {
            uint2 vx, vy;
            vx.x = pk(fmaf(px[k].x, .5f, .5f), fmaf(px[k].y, .5f, .5f));
            vx.y = pk(fmaf(px[k].z, .5f, .5f), fmaf(px[k].w, .5f, .5f));
            vy.x = pk(fmaf(py[k].x, .5f, .5f), fmaf(py[k].y, .5f, .5f));
            vy.y = pk(fmaf(py[k].z, .5f, .5f), fmaf(py[k].w, .5f, .5f));
            *(uint2*)&stg[wv][0][srow[k]][2 * scc[k]] = vx;
            *(uint2*)&stg[wv][1][srow[k]][2 * scc[k]] = vy;
        }
    };

    // conv-W task: 4 output cols (quad qq) of row r; window halves b = t+3
    auto CONVW = [&]() {
        const int r  = lane >> 2;
        const int qq = lane & 3;
        unsigned int dx[10], dy[10];
#pragma unroll
        for (int u = 0; u < 5; ++u) {
            const uint2 vx = *(const uint2*)&stg[wv][0][r][2 * qq + 2 * u];
            const uint2 vy = *(const uint2*)&stg[wv][1][r][2 * qq + 2 * u];
            dx[2 * u] = vx.x; dx[2 * u + 1] = vx.y;
            dy[2 * u] = vy.x; dy[2 * u + 1] = vy.y;
        }
        __half2 aA[5], aB[5];
#pragma unroll
        for (int f = 0; f < 5; ++f) { aA[f] = u2h2(0u); aB[f] = u2h2(0u); }
#pragma unroll
        for (int t5 = 0; t5 < K; ++t5) {
            const int bb = t5 + 3;
            unsigned int xa, xb, ya, yb;
            if ((bb & 1) == 0) {
                xa = dx[bb >> 1]; xb = dx[(bb >> 1) + 1];
                ya = dy[bb >> 1]; yb = dy[(bb >> 1) + 1];
            } else {
                xa = __builtin_amdgcn_alignbit(dx[(bb + 1) >> 1], dx[bb >> 1], 16);
                xb = __builtin_amdgcn_alignbit(dx[(bb + 3) >> 1], dx[(bb + 1) >> 1], 16);
                ya = __builtin_amdgcn_alignbit(dy[(bb + 1) >> 1], dy[bb >> 1], 16);
                yb = __builtin_amdgcn_alignbit(dy[(bb + 3) >> 1], dy[(bb + 1) >> 1], 16);
            }
            const __half2 g   = u2h2(gw.g2[t5]);
            const __half2 hxa = u2h2(xa), hxb = u2h2(xb);
            const __half2 hya = u2h2(ya), hyb = u2h2(yb);
            aA[0] = __hfma2(g, hxa, aA[0]);  aB[0] = __hfma2(g, hxb, aB[0]);
            aA[1] = __hfma2(g, hya, aA[1]);  aB[1] = __hfma2(g, hyb, aB[1]);
            aA[2] = __hfma2(g, __hmul2(hxa, hxa), aA[2]);
            aB[2] = __hfma2(g, __hmul2(hxb, hxb), aB[2]);
            aA[3] = __hfma2(g, __hmul2(hya, hya), aA[3]);
            aB[3] = __hfma2(g, __hmul2(hyb, hyb), aB[3]);
            aA[4] = __hfma2(g, __hmul2(hxa, hya), aA[4]);
            aB[4] = __hfma2(g, __hmul2(hxb, hyb), aB[4]);
        }
#pragma unroll
        for (int f = 0; f < 5; ++f) {
            uint2 o; o.x = h22u(aA[f]); o.y = h22u(aB[f]);
            *(uint2*)&cwl[wv][f][r][2 * qq] = o;
        }
    };

    unsigned int hist[K][5];   // conv-D ring: 2 cols packed per dword
#pragma unroll
    for (int t = 0; t < K; ++t)
#pragma unroll
        for (int f = 0; f < 5; ++f) hist[t][f] = 0u;

    const int th = lane >> 3;   // 0..7; active rows th<6
    const int cp = lane & 7;    // col-pair
    float ssim_acc = 0.0f;

    LOAD(0);

    for (int c = 0; c < 2; ++c) {
#pragma unroll
        for (int j = 0; j < K; ++j) {
            const int ip = c * K + j;

            STORE();                       // stg <- regs (plane ip)
            if (ip + 1 < NP) LOAD(ip + 1); // global prefetch (vmcnt-tracked)
            FENCE();                       // stg visible to whole wave
            CONVW();                       // cwl <- conv-W(stg)
            FENCE();                       // cwl visible to whole wave

            if (th < TH) {
                // conv-H (2 cols, b32 reads), ring insert at static slot j
                __half2 cA[5];
#pragma unroll
                for (int f = 0; f < 5; ++f) cA[f] = u2h2(0u);
#pragma unroll
                for (int t6 = 0; t6 < K; ++t6) {
                    const __half2 g = u2h2(gw.g2[t6]);
#pragma unroll
                    for (int f = 0; f < 5; ++f)
                        cA[f] = __hfma2(g, u2h2(cwl[wv][f][th + t6][cp]), cA[f]);
                }
#pragma unroll
                for (int f = 0; f < 5; ++f) hist[j][f] = h22u(cA[f]);

                // conv-D + SSIM once ring is full
                if (c == 1 || j == K - 1) {
                    __half2 sA[5];
#pragma unroll
                    for (int f = 0; f < 5; ++f) sA[f] = u2h2(0u);
#pragma unroll
                    for (int t7 = 0; t7 < K; ++t7) {
                        const int s = (j + 1 + t7) % K;   // static after unroll
                        const __half2 g = u2h2(gw.g2[t7]);
#pragma unroll
                        for (int f = 0; f < 5; ++f)
                            sA[f] = __hfma2(g, u2h2(hist[s][f]), sA[f]);
                    }
                    const float C1 = 1e-4f, C2 = 9e-4f;
#pragma unroll
                    for (int col = 0; col < 2; ++col) {
                        const float m1  = col ? __high2float(sA[0]) : __low2float(sA[0]);
                        const float m2  = col ? __high2float(sA[1]) : __low2float(sA[1]);
                        const float e11 = col ? __high2float(sA[2]) : __low2float(sA[2]);
                        const float e22 = col ? __high2float(sA[3]) : __low2float(sA[3]);
                        const float e12 = col ? __high2float(sA[4]) : __low2float(sA[4]);
                        const float mu1sq = m1 * m1, mu2sq = m2 * m2, mu12 = m1 * m2;
                        const float s11 = e11 - mu1sq;
                        const float s22 = e22 - mu2sq;
                        const float s12 = e12 - mu12;
                        const float num = (2.f * mu12 + C1) * (2.f * s12 + C2);
                        const float den = (mu1sq + mu2sq + C1) * (s11 + s22 + C2);
                        ssim_acc += num * __builtin_amdgcn_rcpf(den);
                    }
                }
            }
        }
    }

    // ---- reduction: wave shuffle, then one cross-wave combine ----
    float v = ssim_acc;
#pragma unroll
    for (int o = 32; o > 0; o >>= 1) v += __shfl_down(v, o);
    if (lane == 0) wsum[wv] = v;
    __syncthreads();
    if (tid == 0) atomicAdd(acc_g, (double)(wsum[0] + wsum[1] + wsum[2] + wsum[3]));
}

__global__ void k4_final(const double* __restrict__ acc, float* __restrict__ out) {
    if (threadIdx.x == 0) {
        const double n = (double)((size_t)Dd * Hh * Ww);
        out[0] = (float)(1.0 - (*acc) / n);
    }
}

// host-side float -> half (RNE)
static unsigned short f2h(float x) {
    unsigned int u; memcpy(&u, &x, 4);
    unsigned int s = (u >> 16) & 0x8000u;
    int e = (int)((u >> 23) & 0xffu) - 112;
    unsigned int m = u & 0x7fffffu;
    if (e <= 0) return (unsigned short)s;
    unsigned int mant = m + 0xFFFu + ((m >> 13) & 1u);
    if (mant & 0x800000u) { mant = 0; e += 1; }
    return (unsigned short)(s | ((unsigned)e << 10) | (mant >> 13));
}

extern "C" void kernel_launch(void* const* d_in, const int* in_sizes, int n_in,
                              void* d_out, int out_size, void* d_ws, size_t ws_size,
                              hipStream_t stream) {
    const float* gr = (const float*)d_in[0];
    const float* gt = (const float*)d_in[1];
    float* out = (float*)d_out;

    // 1D normalized gaussian (exact outer-product factorization of the 3D window)
    GW gw;
    {
        double e[K], s = 0.0;
        for (int i = 0; i < K; ++i) {
            const double a = (double)((i - R) * (i - R));
            e[i] = exp(-a / (2.0 * 1.5 * 1.5));
            s += e[i];
        }
        for (int i = 0; i < K; ++i) {
            unsigned short h = f2h((float)(e[i] / s));
            gw.g2[i] = (unsigned int)h | ((unsigned int)h << 16);
        }
    }

    double* acc = (double*)d_ws;
    (void)hipMemsetAsync(d_ws, 0, sizeof(double), stream);

    // 4 waves/block, each wave owns an independent 16x6x12 tile
    dim3 grid(Ww / TW / 4, Hh / TH, Dd / DC);   // 3 x 32 x 16 = 1536 blocks
    fused_ssim<<<grid, 256, 0, stream>>>(gr, gt, gw, acc);

    k4_final<<<1, 64, 0, stream>>>(acc, out);
}

// Round 10
// 101.729 us; speedup vs baseline: 1.4373x; 1.1284x over previous
//
#include <hip/hip_runtime.h>
#include <hip/hip_fp16.h>
#include <math.h>
#include <string.h>

#define Dd 192
#define Hh 192
#define Ww 192
#define K  11
#define R  5

#define TW 16             // wave tile width (output cols)
#define TH 6              // wave tile height (output rows)
#define DC 12             // output planes per chunk
#define NP 22             // input planes per chunk
#define HR 16             // halo rows = TH + 2R
#define SROW 36           // stg row stride in dwords (8 groups*4 + 4 pad; quad-stride 9 -> conflict-free)
#define CROW 36           // cwl row stride in dwords (8 pairs*4 + 4 pad)
#define C2ROW 9           // cwl2 (xy field) row stride in dwords (odd -> conflict-free)

struct GW { unsigned int g2[K]; };   // half2(g,g) bit patterns

static __device__ __forceinline__ __half2 u2h2(unsigned int u) {
    union { unsigned int u; __half2 h; } x; x.u = u; return x.h;
}
static __device__ __forceinline__ unsigned int h22u(__half2 h) {
    union { __half2 h; unsigned int u; } x; x.h = h; return x.u;
}
static __device__ __forceinline__ unsigned int pk(float a, float b) {
    typedef __fp16 f16x2 __attribute__((ext_vector_type(2)));
    f16x2 r = __builtin_amdgcn_cvt_pkrtz(a, b);
    union { f16x2 v; unsigned int u; } x; x.v = r; return x.u;
}

// Wave-level phase fence: drain our DS ops, pin compiler/scheduler order.
#define FENCE() do { asm volatile("s_waitcnt lgkmcnt(0)" ::: "memory"); \
                     __builtin_amdgcn_sched_barrier(0); } while (0)

__global__ __launch_bounds__(256, 4) void fused_ssim(
    const float* __restrict__ gr, const float* __restrict__ gt,
    GW gw, double* __restrict__ acc_g)
{
    __shared__ __align__(16) unsigned int stg[4][HR][SROW];   // {x01,x23,y01,y23} per 4-col group
    __shared__ __align__(16) unsigned int cwl[4][HR][CROW];   // {cx,cy,cxx,cyy} per col-pair
    __shared__ unsigned int cwl2[4][HR][C2ROW];               // cxy per col-pair
    __shared__ float wsum[4];

    const int tid  = threadIdx.x;
    const int wv   = tid >> 6;
    const int lane = tid & 63;

    const int w0 = (blockIdx.x * 4 + wv) * TW;
    const int h0 = blockIdx.y * TH;
    const int d0 = blockIdx.z * DC;

    // ---- staging geometry: 2 b128 tasks (row r, group g) per lane ----
    int saddr[2]; int srw[2], sg[2]; unsigned int amask[2];
#pragma unroll
    for (int k = 0; k < 2; ++k) {
        const int t = lane + 64 * k;
        const int r = t >> 3;
        const int g = t & 7;
        srw[k] = r; sg[k] = g;
        const int gh   = h0 - R + r;
        const bool rok = (gh >= 0) && (gh < Hh);
        const int ghc  = gh < 0 ? 0 : (gh >= Hh ? Hh - 1 : gh);
        const int gx0  = w0 - 8 + 4 * g;               // aligned 4-col group
        const bool qok = (gx0 >= 0) && (gx0 + 3 < Ww); // fully in or out
        const int gxc  = gx0 < 0 ? 0 : (gx0 > Ww - 4 ? Ww - 4 : gx0);
        saddr[k] = ghc * Ww + gxc;
        amask[k] = (rok && qok) ? 0x38003800u : 0u;    // half2(0.5,0.5) or 0
    }

    float4 px[2], py[2];

    auto LOAD = [&](int p) {   // raw loads, clamped addresses, no masking
        const int z = d0 - R + p;
        const bool zok = (z >= 0) && (z < Dd);
        const int zb = (zok ? z : 0) * Hh * Ww;
#pragma unroll
        for (int k = 0; k < 2; ++k) {
            px[k] = *(const float4*)(gr + zb + saddr[k]);
            py[k] = *(const float4*)(gt + zb + saddr[k]);
        }
    };

    // masked rescale-and-pack: out = raw*A + A, A = 0.5*mask  ( == ((v+1)/2)*mask )
    auto STORE = [&](int ip) {
        const int z = d0 - R + ip;
        const bool zok = (z >= 0) && (z < Dd);
#pragma unroll
        for (int k = 0; k < 2; ++k) {
            const unsigned int am = zok ? amask[k] : 0u;
            const __half2 A = u2h2(am);
            uint4 o;
            o.x = h22u(__hfma2(u2h2(pk(px[k].x, px[k].y)), A, A));
            o.y = h22u(__hfma2(u2h2(pk(px[k].z, px[k].w)), A, A));
            o.z = h22u(__hfma2(u2h2(pk(py[k].x, py[k].y)), A, A));
            o.w = h22u(__hfma2(u2h2(pk(py[k].z, py[k].w)), A, A));
            *(uint4*)&stg[wv][srw[k]][4 * sg[k]] = o;
        }
    };

    // conv-W: each lane does 4 out cols (row r, quad qq); 5 b128 reads
    auto CONVW = [&]() {
        const int r  = lane >> 2;
        const int qq = lane & 3;
        unsigned int dx[10], dy[10];
#pragma unroll
        for (int u = 0; u < 5; ++u) {
            const uint4 G = *(const uint4*)&stg[wv][r][4 * (qq + u)];
            dx[2 * u] = G.x; dx[2 * u + 1] = G.y;
            dy[2 * u] = G.z; dy[2 * u + 1] = G.w;
        }
        __half2 aA[5], aB[5];
#pragma unroll
        for (int f = 0; f < 5; ++f) { aA[f] = u2h2(0u); aB[f] = u2h2(0u); }
#pragma unroll
        for (int t5 = 0; t5 < K; ++t5) {
            const int bb = t5 + 3;
            unsigned int xa, xb, ya, yb;
            if ((bb & 1) == 0) {
                xa = dx[bb >> 1]; xb = dx[(bb >> 1) + 1];
                ya = dy[bb >> 1]; yb = dy[(bb >> 1) + 1];
            } else {
                xa = __builtin_amdgcn_alignbit(dx[(bb + 1) >> 1], dx[bb >> 1], 16);
                xb = __builtin_amdgcn_alignbit(dx[(bb + 3) >> 1], dx[(bb + 1) >> 1], 16);
                ya = __builtin_amdgcn_alignbit(dy[(bb + 1) >> 1], dy[bb >> 1], 16);
                yb = __builtin_amdgcn_alignbit(dy[(bb + 3) >> 1], dy[(bb + 1) >> 1], 16);
            }
            const __half2 g   = u2h2(gw.g2[t5]);
            const __half2 hxa = u2h2(xa), hxb = u2h2(xb);
            const __half2 hya = u2h2(ya), hyb = u2h2(yb);
            aA[0] = __hfma2(g, hxa, aA[0]);  aB[0] = __hfma2(g, hxb, aB[0]);
            aA[1] = __hfma2(g, hya, aA[1]);  aB[1] = __hfma2(g, hyb, aB[1]);
            aA[2] = __hfma2(g, __hmul2(hxa, hxa), aA[2]);
            aB[2] = __hfma2(g, __hmul2(hxb, hxb), aB[2]);
            aA[3] = __hfma2(g, __hmul2(hya, hya), aA[3]);
            aB[3] = __hfma2(g, __hmul2(hyb, hyb), aB[3]);
            aA[4] = __hfma2(g, __hmul2(hxa, hya), aA[4]);
            aB[4] = __hfma2(g, __hmul2(hxb, hyb), aB[4]);
        }
        uint4 oA, oB;
        oA.x = h22u(aA[0]); oA.y = h22u(aA[1]); oA.z = h22u(aA[2]); oA.w = h22u(aA[3]);
        oB.x = h22u(aB[0]); oB.y = h22u(aB[1]); oB.z = h22u(aB[2]); oB.w = h22u(aB[3]);
        *(uint4*)&cwl[wv][r][4 * (2 * qq)]     = oA;
        *(uint4*)&cwl[wv][r][4 * (2 * qq + 1)] = oB;
        cwl2[wv][r][2 * qq]     = h22u(aA[4]);
        cwl2[wv][r][2 * qq + 1] = h22u(aB[4]);
    };

    unsigned int hist[K][5];   // conv-D ring: 2 cols packed per dword
#pragma unroll
    for (int t = 0; t < K; ++t)
#pragma unroll
        for (int f = 0; f < 5; ++f) hist[t][f] = 0u;

    const int th = lane >> 3;   // 0..7; active rows th<6
    const int cp = lane & 7;    // col-pair 0..7
    float ssim_acc = 0.0f;

    LOAD(0);

    for (int c = 0; c < 2; ++c) {
#pragma unroll
        for (int j = 0; j < K; ++j) {
            const int ip = c * K + j;

            STORE(ip);                     // stg <- regs (plane ip)
            if (ip + 1 < NP) LOAD(ip + 1); // global prefetch
            FENCE();                       // stg visible to whole wave
            CONVW();                       // cwl <- conv-W(stg)
            FENCE();                       // cwl visible to whole wave

            if (th < TH) {
                // conv-H: 11 b128 + 11 b32 reads, ring insert at static slot j
                __half2 c0 = u2h2(0u), c1 = u2h2(0u), c2 = u2h2(0u),
                        c3 = u2h2(0u), c4 = u2h2(0u);
#pragma unroll
                for (int t6 = 0; t6 < K; ++t6) {
                    const uint4 v = *(const uint4*)&cwl[wv][th + t6][4 * cp];
                    const unsigned int v4 = cwl2[wv][th + t6][cp];
                    const __half2 g = u2h2(gw.g2[t6]);
                    c0 = __hfma2(g, u2h2(v.x), c0);
                    c1 = __hfma2(g, u2h2(v.y), c1);
                    c2 = __hfma2(g, u2h2(v.z), c2);
                    c3 = __hfma2(g, u2h2(v.w), c3);
                    c4 = __hfma2(g, u2h2(v4),  c4);
                }
                hist[j][0] = h22u(c0); hist[j][1] = h22u(c1); hist[j][2] = h22u(c2);
                hist[j][3] = h22u(c3); hist[j][4] = h22u(c4);

                // conv-D + SSIM once ring is full
                if (c == 1 || j == K - 1) {
                    __half2 sA[5];
#pragma unroll
                    for (int f = 0; f < 5; ++f) sA[f] = u2h2(0u);
#pragma unroll
                    for (int t7 = 0; t7 < K; ++t7) {
                        const int s = (j + 1 + t7) % K;   // static after unroll
                        const __half2 g = u2h2(gw.g2[t7]);
#pragma unroll
                        for (int f = 0; f < 5; ++f)
                            sA[f] = __hfma2(g, u2h2(hist[s][f]), sA[f]);
                    }
                    const float C1 = 1e-4f, C2 = 9e-4f;
#pragma unroll
                    for (int col = 0; col < 2; ++col) {
                        const float m1  = col ? __high2float(sA[0]) : __low2float(sA[0]);
                        const float m2  = col ? __high2float(sA[1]) : __low2float(sA[1]);
                        const float e11 = col ? __high2float(sA[2]) : __low2float(sA[2]);
                        const float e22 = col ? __high2float(sA[3]) : __low2float(sA[3]);
                        const float e12 = col ? __high2float(sA[4]) : __low2float(sA[4]);
                        const float mu1sq = m1 * m1, mu2sq = m2 * m2, mu12 = m1 * m2;
                        const float s11 = e11 - mu1sq;
                        const float s22 = e22 - mu2sq;
                        const float s12 = e12 - mu12;
                        const float num = (2.f * mu12 + C1) * (2.f * s12 + C2);
                        const float den = (mu1sq + mu2sq + C1) * (s11 + s22 + C2);
                        ssim_acc += num * __builtin_amdgcn_rcpf(den);
                    }
                }
            }
        }
    }

    // ---- reduction: wave shuffle, then one cross-wave combine ----
    float v = ssim_acc;
#pragma unroll
    for (int o = 32; o > 0; o >>= 1) v += __shfl_down(v, o);
    if (lane == 0) wsum[wv] = v;
    __syncthreads();
    if (tid == 0) atomicAdd(acc_g, (double)(wsum[0] + wsum[1] + wsum[2] + wsum[3]));
}

__global__ void k4_final(const double* __restrict__ acc, float* __restrict__ out) {
    if (threadIdx.x == 0) {
        const double n = (double)((size_t)Dd * Hh * Ww);
        out[0] = (float)(1.0 - (*acc) / n);
    }
}

// host-side float -> half (RNE)
static unsigned short f2h(float x) {
    unsigned int u; memcpy(&u, &x, 4);
    unsigned int s = (u >> 16) & 0x8000u;
    int e = (int)((u >> 23) & 0xffu) - 112;
    unsigned int m = u & 0x7fffffu;
    if (e <= 0) return (unsigned short)s;
    unsigned int mant = m + 0xFFFu + ((m >> 13) & 1u);
    if (mant & 0x800000u) { mant = 0; e += 1; }
    return (unsigned short)(s | ((unsigned)e << 10) | (mant >> 13));
}

extern "C" void kernel_launch(void* const* d_in, const int* in_sizes, int n_in,
                              void* d_out, int out_size, void* d_ws, size_t ws_size,
                              hipStream_t stream) {
    const float* gr = (const float*)d_in[0];
    const float* gt = (const float*)d_in[1];
    float* out = (float*)d_out;

    // 1D normalized gaussian (exact outer-product factorization of the 3D window)
    GW gw;
    {
        double e[K], s = 0.0;
        for (int i = 0; i < K; ++i) {
            const double a = (double)((i - R) * (i - R));
            e[i] = exp(-a / (2.0 * 1.5 * 1.5));
            s += e[i];
        }
        for (int i = 0; i < K; ++i) {
            unsigned short h = f2h((float)(e[i] / s));
            gw.g2[i] = (unsigned int)h | ((unsigned int)h << 16);
        }
    }

    double* acc = (double*)d_ws;
    (void)hipMemsetAsync(d_ws, 0, sizeof(double), stream);

    // 4 waves/block, each wave owns an independent 16x6x12 tile
    dim3 grid(Ww / TW / 4, Hh / TH, Dd / DC);   // 3 x 32 x 16 = 1536 blocks
    fused_ssim<<<grid, 256, 0, stream>>>(gr, gt, gw, acc);

    k4_final<<<1, 64, 0, stream>>>(acc, out);
}

// Round 11
// 64.248 us; speedup vs baseline: 2.2758x; 1.5834x over previous
//
#include <hip/hip_runtime.h>
#include <hip/hip_fp16.h>
#include <math.h>
#include <string.h>

#define Dd 192
#define Hh 192
#define Ww 192
#define K  11
#define R  5

#define DC 16             // output planes per wave-tile chunk
#define NP 26             // input planes per chunk (DC + 2R)

typedef _Float16 h4  __attribute__((ext_vector_type(4)));
typedef float    f32x4 __attribute__((ext_vector_type(4)));

struct GWF { float gf[K]; unsigned int g2[K]; };  // f32 + half2(g,g) forms

static __device__ __forceinline__ __half2 u2h2(unsigned int u) {
    union { unsigned int u; __half2 h; } x; x.u = u; return x.h;
}
static __device__ __forceinline__ unsigned int h22u(__half2 h) {
    union { __half2 h; unsigned int u; } x; x.h = h; return x.u;
}
static __device__ __forceinline__ unsigned int pk(float a, float b) {
    typedef __fp16 f16x2 __attribute__((ext_vector_type(2)));
    f16x2 r = __builtin_amdgcn_cvt_pkrtz(a, b);
    union { f16x2 v; unsigned int u; } x; x.v = r; return x.u;
}
// banded-weight select: g[j] for j in [0,10], else 0
static __device__ __forceinline__ float wsel(int j, const GWF& G) {
    float v = 0.f;
#pragma unroll
    for (int t = 0; t < K; ++t) v = (j == t) ? G.gf[t] : v;
    return v;
}
// D = A(16x16 f16) * B(16x16 f16) + C, fragments as 2 dwords each
static __device__ __forceinline__ f32x4 MFMA(unsigned int a0, unsigned int a1,
                                             unsigned int b0, unsigned int b1,
                                             f32x4 c) {
    union { unsigned int u[2]; h4 h; } A, B;
    A.u[0] = a0; A.u[1] = a1; B.u[0] = b0; B.u[1] = b1;
    return __builtin_amdgcn_mfma_f32_16x16x16f16(A.h, B.h, c, 0, 0, 0);
}

// Fully register-resident fused SSIM: global->regs (MFMA A-layout),
// conv-W = banded MFMA, conv-H = banded MFMA chained off conv-W's D,
// conv-D = fp16 register ring, SSIM + wave reduce. No LDS in the hot loop.
__global__ __launch_bounds__(256, 2) void fused_ssim(
    const float* __restrict__ gr, const float* __restrict__ gt,
    GWF gw, double* __restrict__ acc_g)
{
    __shared__ float wsum[4];

    const int tid  = threadIdx.x;
    const int wv   = tid >> 6;
    const int lane = tid & 63;
    const int n16  = lane & 15;    // MFMA 16-index (row of A / col of B,D)
    const int g4   = lane >> 4;    // lane group 0..3

    // XCD-chunked swizzle, z-fastest (D-halo neighbors stay on one XCD's L2)
    const int bid  = blockIdx.x;                 // 0..431
    const int wgid = (bid & 7) * 54 + (bid >> 3);
    const int z4   = wgid % 12;
    const int yx   = wgid / 12;
    const int hy   = yx % 12;
    const int bx   = yx / 12;

    const int w0 = (bx * 4 + wv) * 16;
    const int h0 = hy * 16;
    const int d0 = z4 * DC;

    // ---- load geometry: (rc,kc): row = h0-5+16rc+n16, col = w0-8+16kc+4*g4
    int addr[2][2]; float amf[2][2];
#pragma unroll
    for (int rc = 0; rc < 2; ++rc)
#pragma unroll
    for (int kc = 0; kc < 2; ++kc) {
        const int gh   = h0 - R + 16 * rc + n16;
        const bool rok = (gh >= 0) && (gh < Hh);
        const int ghc  = gh < 0 ? 0 : (gh >= Hh ? Hh - 1 : gh);
        const int gx   = w0 - 8 + 16 * kc + 4 * g4;
        const bool cok = (gx >= 0) && (gx + 3 < Ww);
        const int gxc  = gx < 0 ? 0 : (gx > Ww - 4 ? Ww - 4 : gx);
        addr[rc][kc] = ghc * Ww + gxc;
        amf[rc][kc]  = (rok && cok) ? 0.5f : 0.f;
    }

    // ---- banded weight fragments (computed once) ----
    // conv-W B-frag: B[k][n]=g[k-n-3], n=n16 (out col), k=16kc+4g4+i
    unsigned int Bw[2][2];
#pragma unroll
    for (int kc = 0; kc < 2; ++kc) {
        const int kb = 16 * kc + 4 * g4 - n16 - 3;
        Bw[kc][0] = pk(wsel(kb + 0, gw), wsel(kb + 1, gw));
        Bw[kc][1] = pk(wsel(kb + 2, gw), wsel(kb + 3, gw));
    }
    // conv-H A-frag: A[m][k]=g[k-m], m=n16 (out row), k=16kc+4g4+i
    unsigned int Ah[2][2];
#pragma unroll
    for (int kc = 0; kc < 2; ++kc) {
        const int kb = 16 * kc + 4 * g4 - n16;
        Ah[kc][0] = pk(wsel(kb + 0, gw), wsel(kb + 1, gw));
        Ah[kc][1] = pk(wsel(kb + 2, gw), wsel(kb + 3, gw));
    }

    float4 px[2][2], py[2][2];
    auto LOADP = [&](int p) {
        const int z  = d0 - R + p;
        const bool zok = (z >= 0) && (z < Dd);
        const int zb = (zok ? z : 0) * Hh * Ww;
#pragma unroll
        for (int rc = 0; rc < 2; ++rc)
#pragma unroll
        for (int kc = 0; kc < 2; ++kc) {
            px[rc][kc] = *(const float4*)(gr + zb + addr[rc][kc]);
            py[rc][kc] = *(const float4*)(gt + zb + addr[rc][kc]);
        }
    };

    unsigned int hist[K][5][2];   // conv-D ring: 11 planes x 5 fields x 4 rows (2 fp16 pairs)
#pragma unroll
    for (int t = 0; t < K; ++t)
#pragma unroll
        for (int f = 0; f < 5; ++f) { hist[t][f][0] = 0u; hist[t][f][1] = 0u; }

    float ssim_acc = 0.0f;
    LOADP(0);

    for (int c = 0; c < 3; ++c) {
#pragma unroll
        for (int j = 0; j < K; ++j) {
            const int ip = c * K + j;
            if (ip < NP) {
                const int z = d0 - R + ip;
                const bool zok = (z >= 0) && (z < Dd);

                // ---- stage fields (f16 A-frags) + conv-W MFMAs, per row-chunk
                unsigned int b2[5][2][2];   // conv-H B operand: field, rc, 2 dwords
#pragma unroll
                for (int rc = 0; rc < 2; ++rc) {
                    unsigned int stgf[5][2][2];   // field, kc, dword (transient)
#pragma unroll
                    for (int kc = 0; kc < 2; ++kc) {
                        const float A = zok ? amf[rc][kc] : 0.f;
                        const float4 X = px[rc][kc], Y = py[rc][kc];
                        const float xs0 = fmaf(X.x, A, A), xs1 = fmaf(X.y, A, A);
                        const float xs2 = fmaf(X.z, A, A), xs3 = fmaf(X.w, A, A);
                        const float ys0 = fmaf(Y.x, A, A), ys1 = fmaf(Y.y, A, A);
                        const float ys2 = fmaf(Y.z, A, A), ys3 = fmaf(Y.w, A, A);
                        stgf[0][kc][0] = pk(xs0, xs1);          stgf[0][kc][1] = pk(xs2, xs3);
                        stgf[1][kc][0] = pk(ys0, ys1);          stgf[1][kc][1] = pk(ys2, ys3);
                        stgf[2][kc][0] = pk(xs0*xs0, xs1*xs1);  stgf[2][kc][1] = pk(xs2*xs2, xs3*xs3);
                        stgf[3][kc][0] = pk(ys0*ys0, ys1*ys1);  stgf[3][kc][1] = pk(ys2*ys2, ys3*ys3);
                        stgf[4][kc][0] = pk(xs0*ys0, xs1*ys1);  stgf[4][kc][1] = pk(xs2*ys2, xs3*ys3);
                    }
#pragma unroll
                    for (int f = 0; f < 5; ++f) {
                        f32x4 cw = {0.f, 0.f, 0.f, 0.f};
                        cw = MFMA(stgf[f][0][0], stgf[f][0][1], Bw[0][0], Bw[0][1], cw);
                        cw = MFMA(stgf[f][1][0], stgf[f][1][1], Bw[1][0], Bw[1][1], cw);
                        b2[f][rc][0] = pk(cw[0], cw[1]);
                        b2[f][rc][1] = pk(cw[2], cw[3]);
                    }
                }

                if (ip + 1 < NP) LOADP(ip + 1);   // prefetch next plane

                // ---- conv-H MFMAs (chained: b2 is already in B-layout) ----
#pragma unroll
                for (int f = 0; f < 5; ++f) {
                    f32x4 ch = {0.f, 0.f, 0.f, 0.f};
                    ch = MFMA(Ah[0][0], Ah[0][1], b2[f][0][0], b2[f][0][1], ch);
                    ch = MFMA(Ah[1][0], Ah[1][1], b2[f][1][0], b2[f][1][1], ch);
                    hist[j][f][0] = pk(ch[0], ch[1]);   // rows 4g4+0,1 (col n16)
                    hist[j][f][1] = pk(ch[2], ch[3]);   // rows 4g4+2,3
                }

                // ---- conv-D + SSIM (ring full from ip>=10) ----
                if (ip >= 2 * R) {
                    __half2 s[5][2];
#pragma unroll
                    for (int f = 0; f < 5; ++f) { s[f][0] = u2h2(0u); s[f][1] = u2h2(0u); }
#pragma unroll
                    for (int t7 = 0; t7 < K; ++t7) {
                        const int sl = (j + 1 + t7) % K;   // static after unroll
                        const __half2 g = u2h2(gw.g2[t7]);
#pragma unroll
                        for (int f = 0; f < 5; ++f) {
                            s[f][0] = __hfma2(g, u2h2(hist[sl][f][0]), s[f][0]);
                            s[f][1] = __hfma2(g, u2h2(hist[sl][f][1]), s[f][1]);
                        }
                    }
                    const float C1 = 1e-4f, C2 = 9e-4f;
#pragma unroll
                    for (int p = 0; p < 2; ++p) {
#pragma unroll
                        for (int col = 0; col < 2; ++col) {
                            const float m1  = col ? __high2float(s[0][p]) : __low2float(s[0][p]);
                            const float m2  = col ? __high2float(s[1][p]) : __low2float(s[1][p]);
                            const float e11 = col ? __high2float(s[2][p]) : __low2float(s[2][p]);
                            const float e22 = col ? __high2float(s[3][p]) : __low2float(s[3][p]);
                            const float e12 = col ? __high2float(s[4][p]) : __low2float(s[4][p]);
                            const float mu1sq = m1 * m1, mu2sq = m2 * m2, mu12 = m1 * m2;
                            const float s11 = e11 - mu1sq;
                            const float s22 = e22 - mu2sq;
                            const float s12 = e12 - mu12;
                            const float num = (2.f * mu12 + C1) * (2.f * s12 + C2);
                            const float den = (mu1sq + mu2sq + C1) * (s11 + s22 + C2);
                            ssim_acc += num * __builtin_amdgcn_rcpf(den);
                        }
                    }
                }
            }
        }
    }

    // ---- reduction: wave shuffle, then one cross-wave combine ----
    float v = ssim_acc;
#pragma unroll
    for (int o = 32; o > 0; o >>= 1) v += __shfl_down(v, o);
    if (lane == 0) wsum[wv] = v;
    __syncthreads();
    if (tid == 0) atomicAdd(acc_g, (double)(wsum[0] + wsum[1] + wsum[2] + wsum[3]));
}

__global__ void k4_final(const double* __restrict__ acc, float* __restrict__ out) {
    if (threadIdx.x == 0) {
        const double n = (double)((size_t)Dd * Hh * Ww);
        out[0] = (float)(1.0 - (*acc) / n);
    }
}

// host-side float -> half (RNE)
static unsigned short f2h(float x) {
    unsigned int u; memcpy(&u, &x, 4);
    unsigned int s = (u >> 16) & 0x8000u;
    int e = (int)((u >> 23) & 0xffu) - 112;
    unsigned int m = u & 0x7fffffu;
    if (e <= 0) return (unsigned short)s;
    unsigned int mant = m + 0xFFFu + ((m >> 13) & 1u);
    if (mant & 0x800000u) { mant = 0; e += 1; }
    return (unsigned short)(s | ((unsigned)e << 10) | (mant >> 13));
}

extern "C" void kernel_launch(void* const* d_in, const int* in_sizes, int n_in,
                              void* d_out, int out_size, void* d_ws, size_t ws_size,
                              hipStream_t stream) {
    const float* gr = (const float*)d_in[0];
    const float* gt = (const float*)d_in[1];
    float* out = (float*)d_out;

    // 1D normalized gaussian (exact outer-product factorization of the 3D window)
    GWF gw;
    {
        double e[K], s = 0.0;
        for (int i = 0; i < K; ++i) {
            const double a = (double)((i - R) * (i - R));
            e[i] = exp(-a / (2.0 * 1.5 * 1.5));
            s += e[i];
        }
        for (int i = 0; i < K; ++i) {
            gw.gf[i] = (float)(e[i] / s);
            unsigned short h = f2h(gw.gf[i]);
            gw.g2[i] = (unsigned int)h | ((unsigned int)h << 16);
        }
    }

    double* acc = (double*)d_ws;
    (void)hipMemsetAsync(d_ws, 0, sizeof(double), stream);

    // 4 waves/block; wave tile = 16 cols x 16 rows x 16 planes
    // grid: 3(bx) x 12(h) x 12(z) = 432 blocks, 1D with XCD swizzle in-kernel
    fused_ssim<<<432, 256, 0, stream>>>(gr, gt, gw, acc);

    k4_final<<<1, 64, 0, stream>>>(acc, out);
}